// Round 1
// baseline (655.169 us; speedup 1.0000x reference)
//
#include <hip/hip_runtime.h>
#include <hip/hip_bf16.h>
#include <math.h>

#define NB 4096
#define NN 64
#define NM 4
#define NF 128
#define NOBS 64
#define ND 64
#define NH 4
#define NLAYER 2
#define NFF 128
#define NHID 64
#define NOUT 8
#define EPSC 1e-6f

struct GParams {
    const float* x_anc; const float* g_anc; const float* x_nei; const float* ew_anc;
    const float* W_anc; const float* b_anc;
    const float* Wv_emb; const float* bv_emb; const float* Wv_val; const float* bv_val;
    const float* r_Win; const float* r_bin; const float* r_lng; const float* r_lnb;
    const float* r_W1; const float* r_b1; const float* r_W2; const float* r_b2;
    const float* r_Wview; const float* r_bview; const float* r_Wmode; const float* r_bmode;
    const float* log_tau;
    const float* L_Wq; const float* L_Wk; const float* L_Wv; const float* L_Wo;
    const float* L_ln1g; const float* L_ln1b; const float* L_ln2g; const float* L_ln2b;
    const float* L_Wf1; const float* L_bf1; const float* L_Wf2; const float* L_bf2;
    const float* p_lng; const float* p_lnb; const float* p_W1; const float* p_b1;
    const float* p_W2; const float* p_b2;
    float* out;
};

__device__ __forceinline__ float gelu_f(float x) {
    return 0.5f * x * (1.0f + erff(x * 0.7071067811865476f));
}
__device__ __forceinline__ float wsum64(float v) {
#pragma unroll
    for (int off = 32; off > 0; off >>= 1) v += __shfl_xor(v, off, 64);
    return v;
}
__device__ __forceinline__ float wmax64(float v) {
#pragma unroll
    for (int off = 32; off > 0; off >>= 1) v = fmaxf(v, __shfl_xor(v, off, 64));
    return v;
}

__global__ __launch_bounds__(256, 2)
void gora_fused(GParams P)
{
    const int b = blockIdx.x;
    const int t = threadIdx.x;
    const int lane = t & 63;
    const int wave = t >> 6;

    // ---- LDS (total ~58.5 KB -> 2 blocks/CU) ----
    __shared__ __hip_bfloat16 xsf[NN * NF];          // 16 KB  x_nei[b] in bf16
    __shared__ float hns[NN][ND];                    // 16 KB  h_nei_shared fp32
    __shared__ __hip_bfloat16 kb16[NN][ND + 2];      // 8.25KB K (padded rows: 66 elems)
    __shared__ __hip_bfloat16 vb16[NN][ND + 2];      // 8.25KB V
    __shared__ float ew_s[NN * NM];                  // raw masked ew  [n*4+m]
    __shared__ float winv[NM], wssum[NM];
    __shared__ float xa[NF];
    __shared__ float ga[NOBS];
    __shared__ float xw[NM][NF];
    __shared__ float hv[NM][ND];
    __shared__ float pvc[NM][ND];
    __shared__ float hfin[NHID];
    __shared__ float pi_raw[NH * NM];
    __shared__ float pi_s[NH][NM];
    __shared__ float beta_s[NH];
    __shared__ float gate_s[NH][NN];
    __shared__ float xcur[ND];
    __shared__ float qv[ND];
    __shared__ float attn_s[NH][NN];
    __shared__ float ctx_s[ND];
    __shared__ float ffs[NFF];
    __shared__ float sA[ND];
    __shared__ float sB[ND];

    // ================= loads =================
    {
        float e = P.ew_anc[(size_t)b * NN * NM + t];   // 256 = N*M exactly
        ew_s[t] = (e > 0.0f) ? e : 0.0f;               // ew * (ew>0)
    }
    if (t < NF) xa[t] = P.x_anc[(size_t)b * NF + t];
    else if (t < NF + NOBS) ga[t - NF] = P.g_anc[(size_t)b * NOBS + (t - NF)];
    {
        const float4* xn4 = (const float4*)(P.x_nei + (size_t)b * NN * NF);
#pragma unroll
        for (int i = 0; i < 8; i++) {
            int i4 = t + i * 256;                      // 2048 float4 total
            float4 v4 = xn4[i4];
            __hip_bfloat162 p0, p1;
            p0.x = __float2bfloat16(v4.x); p0.y = __float2bfloat16(v4.y);
            p1.x = __float2bfloat16(v4.z); p1.y = __float2bfloat16(v4.w);
            __hip_bfloat162* dst = (__hip_bfloat162*)&xsf[i4 * 4];
            dst[0] = p0; dst[1] = p1;
        }
    }
    __syncthreads();

    // ======== view-weight norms (t<4) + h_anc (t in [64,128)) ========
    if (t < NM) {
        float s = 0.0f;
        for (int n = 0; n < NN; n++) s += ew_s[n * NM + t];
        float c = fmaxf(s, EPSC);
        winv[t]  = 1.0f / c;
        wssum[t] = s / c;                 // sum of normalized weights (0 or 1-ish)
    }
    if (t >= 64 && t < 128) {
        int d = t - 64;
        float acc = P.b_anc[d];
        for (int f = 0; f < NF; f++) acc += xa[f] * P.W_anc[f * ND + d];
        xcur[d] = acc;                    // x = h_anc
    }
    __syncthreads();

    // ======== xw[m][f] = sum_n w[m,n] * x_nei[n,f] ========
    {
        int f = t & (NF - 1);
        int m0 = t >> 7;                  // wave-uniform (0 or 1)
        float a0 = 0.f, a1 = 0.f;
        for (int n = 0; n < NN; n++) {
            float xv = __bfloat162float(xsf[n * NF + f]);
            a0 += ew_s[n * NM + m0] * xv;
            a1 += ew_s[n * NM + m0 + 2] * xv;
        }
        xw[m0][f]     = a0 * winv[m0];
        xw[m0 + 2][f] = a1 * winv[m0 + 2];
    }

    // ======== h_nei_shared = x_nei @ Wv_emb[0] + bv_emb[0]  (64x128 @ 128x64) ========
    {
        const int d = lane;
        const int n0 = wave * 16;
        float acc[16];
        float bias = P.bv_emb[d];         // m = 0
#pragma unroll
        for (int i = 0; i < 16; i++) acc[i] = bias;
        const float* W0 = P.Wv_emb;       // m = 0 block
        for (int ft = 0; ft < NF; ft += 8) {
            float w0r[8];
#pragma unroll
            for (int j = 0; j < 8; j++) w0r[j] = W0[(ft + j) * ND + d];
#pragma unroll
            for (int i = 0; i < 16; i++) {
                const float4 xr = *(const float4*)&xsf[(n0 + i) * NF + ft]; // 8 bf16
                const __hip_bfloat162* xp = (const __hip_bfloat162*)&xr;
#pragma unroll
                for (int j = 0; j < 4; j++) {
                    acc[i] += __bfloat162float(xp[j].x) * w0r[2 * j];
                    acc[i] += __bfloat162float(xp[j].y) * w0r[2 * j + 1];
                }
            }
        }
#pragma unroll
        for (int i = 0; i < 16; i++) hns[n0 + i][d] = acc[i];
    }
    __syncthreads();

    // ======== per_view_ctx: hv = xw@Wv_emb[m] + s*bv_emb ; pvc = hv@Wv_val[m] + s*bv_val ========
    {
        int m = wave, d = lane;
        float acc = wssum[m] * P.bv_emb[m * ND + d];
        const float* We = P.Wv_emb + (size_t)m * NF * ND;
        for (int f = 0; f < NF; f++) acc += xw[m][f] * We[f * ND + d];
        hv[m][d] = acc;
    }
    __syncthreads();
    {
        int m = wave, d = lane;
        float acc = wssum[m] * P.bv_val[m * ND + d];
        const float* Wv = P.Wv_val + (size_t)m * ND * ND;
        for (int k = 0; k < ND; k++) acc += hv[m][k] * Wv[k * ND + d];
        pvc[m][d] = acc;
    }
    __syncthreads();

    // ======== ctx_vec + r-MLP ========
    if (t < ND) sA[t] = 0.25f * (pvc[0][t] + pvc[1][t] + pvc[2][t] + pvc[3][t]);
    __syncthreads();
    if (t < NHID) {
        float acc = P.r_bin[t];
        for (int f = 0; f < NOBS; f++) acc += ga[f] * P.r_Win[f * NHID + t];
        for (int f = 0; f < ND;   f++) acc += sA[f] * P.r_Win[(NOBS + f) * NHID + t];
        float mean = wsum64(acc) * (1.0f / 64.0f);
        float dv = acc - mean;
        float var = wsum64(dv * dv) * (1.0f / 64.0f);
        float xln = dv * rsqrtf(var + 1e-5f) * P.r_lng[t] + P.r_lnb[t];
        sB[t] = gelu_f(xln);
    }
    __syncthreads();
    if (t < NHID) {
        float acc = P.r_b1[t];
        for (int k = 0; k < NHID; k++) acc += sB[k] * P.r_W1[k * NHID + t];
        sA[t] = gelu_f(acc);
    }
    __syncthreads();
    if (t < NHID) {
        float acc = P.r_b2[t];
        for (int k = 0; k < NHID; k++) acc += sA[k] * P.r_W2[k * NHID + t];
        hfin[t] = gelu_f(acc);
    }
    __syncthreads();

    // ======== pi (softmax over views), beta ========
    if (t < NH * NM) {
        int h = t >> 2, mm = t & 3;
        float acc = P.r_bview[h * NM + mm];
        for (int k = 0; k < NHID; k++) acc += hfin[k] * P.r_Wview[(h * NHID + k) * NM + mm];
        pi_raw[t] = acc;
    }
    if (t >= 64 && t < 64 + NH) {
        int h = t - 64;
        float acc = P.r_bmode[h];
        for (int k = 0; k < NHID; k++) acc += hfin[k] * P.r_Wmode[h * NHID + k];
        beta_s[h] = 1.0f / (1.0f + expf(-acc));
    }
    __syncthreads();
    if (t < NH) {
        float mx = -1e30f;
        for (int mm = 0; mm < NM; mm++) mx = fmaxf(mx, pi_raw[t * NM + mm]);
        float s = 0.f, e[NM];
        for (int mm = 0; mm < NM; mm++) { e[mm] = expf(pi_raw[t * NM + mm] - mx); s += e[mm]; }
        for (int mm = 0; mm < NM; mm++) pi_s[t][mm] = e[mm] / s;
    }
    __syncthreads();

    // ======== gate[h][n] = log(sum_m pi[h,m]*ew_raw[n,m] + EPS) ========
    {
        int h = wave, n = lane;
        float wv = 0.f;
        for (int mm = 0; mm < NM; mm++) wv += pi_s[h][mm] * ew_s[n * NM + mm];
        gate_s[h][n] = logf(wv + EPSC);
    }
    __syncthreads();

    // ======== attention + FF layers ========
    const float inv_tau_scale = 0.25f / expf(P.log_tau[wave]);  // scale=1/sqrt(16)
    for (int l = 0; l < NLAYER; l++) {
        const float* Wq  = P.L_Wq  + l * ND * ND;
        const float* Wk  = P.L_Wk  + l * ND * ND;
        const float* Wvv = P.L_Wv  + l * ND * ND;
        const float* Wo  = P.L_Wo  + l * ND * ND;
        const float* ln1g = P.L_ln1g + l * ND;
        const float* ln1b = P.L_ln1b + l * ND;
        const float* ln2g = P.L_ln2g + l * ND;
        const float* ln2b = P.L_ln2b + l * ND;
        const float* Wf1 = P.L_Wf1 + l * ND * NFF;
        const float* bf1 = P.L_bf1 + l * NFF;
        const float* Wf2 = P.L_Wf2 + l * NFF * ND;
        const float* bf2 = P.L_bf2 + l * ND;

        if (t < ND) {
            float acc = 0.f;
            for (int k = 0; k < ND; k++) acc += xcur[k] * Wq[k * ND + t];
            qv[t] = acc;
        }
        // K/V projections from h_nei_shared (no bias in reference)
        {
            const int d = lane;
            const int n0 = wave * 16;
            float acck[16], accv[16];
#pragma unroll
            for (int i = 0; i < 16; i++) { acck[i] = 0.f; accv[i] = 0.f; }
            for (int kt = 0; kt < ND; kt += 4) {
                float wk[4], wv[4];
#pragma unroll
                for (int j = 0; j < 4; j++) {
                    wk[j] = Wk[(kt + j) * ND + d];
                    wv[j] = Wvv[(kt + j) * ND + d];
                }
#pragma unroll
                for (int i = 0; i < 16; i++) {
                    const float4 hr = *(const float4*)&hns[n0 + i][kt];
                    acck[i] += hr.x * wk[0] + hr.y * wk[1] + hr.z * wk[2] + hr.w * wk[3];
                    accv[i] += hr.x * wv[0] + hr.y * wv[1] + hr.z * wv[2] + hr.w * wv[3];
                }
            }
#pragma unroll
            for (int i = 0; i < 16; i++) {
                kb16[n0 + i][d] = __float2bfloat16(acck[i]);
                vb16[n0 + i][d] = __float2bfloat16(accv[i]);
            }
        }
        __syncthreads();
        // scores + softmax over n (one head per wave)
        {
            int h = wave, n = lane;
            float s = 0.f;
#pragma unroll
            for (int j = 0; j < 16; j++)
                s += qv[h * 16 + j] * __bfloat162float(kb16[n][h * 16 + j]);
            s = s * inv_tau_scale + gate_s[h][n];
            float mx = wmax64(s);
            float e = expf(s - mx);
            float se = wsum64(e);
            attn_s[h][n] = e / se;
        }
        __syncthreads();
        if (t < ND) {
            int h = t >> 4;
            float acc = 0.f;
            for (int n = 0; n < NN; n++) acc += attn_s[h][n] * __bfloat162float(vb16[n][t]);
            ctx_s[t] = acc;
        }
        __syncthreads();
        if (t < ND) {
            float acc = 0.f;
            for (int c = 0; c < ND; c++) acc += ctx_s[c] * Wo[c * ND + t];
            float xv = xcur[t] + acc;
            float mean = wsum64(xv) * (1.0f / 64.0f);
            float dv = xv - mean;
            float var = wsum64(dv * dv) * (1.0f / 64.0f);
            xcur[t] = dv * rsqrtf(var + 1e-5f) * ln1g[t] + ln1b[t];
        }
        __syncthreads();
        if (t < NFF) {
            float acc = bf1[t];
            for (int d = 0; d < ND; d++) acc += xcur[d] * Wf1[d * NFF + t];
            ffs[t] = gelu_f(acc);
        }
        __syncthreads();
        if (t < ND) {
            float acc = bf2[t];
            for (int j = 0; j < NFF; j++) acc += ffs[j] * Wf2[j * ND + t];
            float xv = xcur[t] + acc;
            float mean = wsum64(xv) * (1.0f / 64.0f);
            float dv = xv - mean;
            float var = wsum64(dv * dv) * (1.0f / 64.0f);
            xcur[t] = dv * rsqrtf(var + 1e-5f) * ln2g[t] + ln2b[t];
        }
        __syncthreads();
    }

    // ======== blended + final head ========
    if (t < ND) {
        float acc = 0.f;
#pragma unroll
        for (int h = 0; h < NH; h++) {
            float iso = 0.f;
#pragma unroll
            for (int mm = 0; mm < NM; mm++) iso += pi_s[h][mm] * pvc[mm][t];
            acc += (1.0f - beta_s[h]) * iso + beta_s[h] * xcur[t];
        }
        float bl = acc * 0.25f;
        float mean = wsum64(bl) * (1.0f / 64.0f);
        float dv = bl - mean;
        float var = wsum64(dv * dv) * (1.0f / 64.0f);
        sA[t] = dv * rsqrtf(var + 1e-5f) * P.p_lng[t] + P.p_lnb[t];
    }
    __syncthreads();
    if (t < 32) {
        float acc = P.p_b1[t];
        for (int d = 0; d < ND; d++) acc += sA[d] * P.p_W1[d * 32 + t];
        sB[t] = gelu_f(acc);
    }
    __syncthreads();
    if (t < NOUT) {
        float acc = P.p_b2[t];
        for (int j = 0; j < 32; j++) acc += sB[j] * P.p_W2[j * NOUT + t];
        P.out[(size_t)b * NOUT + t] = acc;
    }
}

extern "C" void kernel_launch(void* const* d_in, const int* in_sizes, int n_in,
                              void* d_out, int out_size, void* d_ws, size_t ws_size,
                              hipStream_t stream)
{
    (void)in_sizes; (void)n_in; (void)d_ws; (void)ws_size; (void)out_size;
    GParams P;
    P.x_anc   = (const float*)d_in[0];
    P.g_anc   = (const float*)d_in[1];
    P.x_nei   = (const float*)d_in[2];
    P.ew_anc  = (const float*)d_in[3];
    P.W_anc   = (const float*)d_in[4];
    P.b_anc   = (const float*)d_in[5];
    P.Wv_emb  = (const float*)d_in[6];
    P.bv_emb  = (const float*)d_in[7];
    P.Wv_val  = (const float*)d_in[8];
    P.bv_val  = (const float*)d_in[9];
    P.r_Win   = (const float*)d_in[10];
    P.r_bin   = (const float*)d_in[11];
    P.r_lng   = (const float*)d_in[12];
    P.r_lnb   = (const float*)d_in[13];
    P.r_W1    = (const float*)d_in[14];
    P.r_b1    = (const float*)d_in[15];
    P.r_W2    = (const float*)d_in[16];
    P.r_b2    = (const float*)d_in[17];
    P.r_Wview = (const float*)d_in[18];
    P.r_bview = (const float*)d_in[19];
    P.r_Wmode = (const float*)d_in[20];
    P.r_bmode = (const float*)d_in[21];
    P.log_tau = (const float*)d_in[22];
    P.L_Wq    = (const float*)d_in[23];
    P.L_Wk    = (const float*)d_in[24];
    P.L_Wv    = (const float*)d_in[25];
    P.L_Wo    = (const float*)d_in[26];
    P.L_ln1g  = (const float*)d_in[27];
    P.L_ln1b  = (const float*)d_in[28];
    P.L_ln2g  = (const float*)d_in[29];
    P.L_ln2b  = (const float*)d_in[30];
    P.L_Wf1   = (const float*)d_in[31];
    P.L_bf1   = (const float*)d_in[32];
    P.L_Wf2   = (const float*)d_in[33];
    P.L_bf2   = (const float*)d_in[34];
    P.p_lng   = (const float*)d_in[35];
    P.p_lnb   = (const float*)d_in[36];
    P.p_W1    = (const float*)d_in[37];
    P.p_b1    = (const float*)d_in[38];
    P.p_W2    = (const float*)d_in[39];
    P.p_b2    = (const float*)d_in[40];
    P.out     = (float*)d_out;
    hipLaunchKernelGGL(gora_fused, dim3(NB), dim3(256), 0, stream, P);
}